// Round 3
// baseline (187.857 us; speedup 1.0000x reference)
//
#include <hip/hip_runtime.h>
#include <hip/hip_cooperative_groups.h>
#include <math.h>

namespace cg = cooperative_groups;

#define NB   64
#define H_   384
#define W_   384
#define NR   12
#define NC   12
#define NP   144     // patches per batch
#define PE   1024    // elements per patch
#define NSEL 36
#define NPART 16     // min/max partials per batch

// ws layout:
// [0, 4096):            float pmin[64][16]
// [4096, 8192):         float pmax[64][16]
// [8192, +64*144*1024): uint8 binned patches [B][144][1024]

__device__ inline int binval(float x, float mn, float denom){
    float nrm = (x - mn) / denom;                 // mirror reference op order exactly
    nrm = fminf(fmaxf(nrm, 0.0f), 1.0f);
    int bn = (int)(nrm * 63.0f);                  // truncation, like astype(int32)
    bn = bn < 0 ? 0 : (bn > 63 ? 63 : bn);
    return bn;
}

__device__ inline unsigned int bytesad(unsigned int a, unsigned int b, unsigned int acc){
#if __has_builtin(__builtin_amdgcn_sad_u8)
    return __builtin_amdgcn_sad_u8(a, b, acc);
#else
    unsigned int s = acc;
    #pragma unroll
    for (int k = 0; k < 4; k++){
        int av = (a >> (8 * k)) & 255;
        int bv = (b >> (8 * k)) & 255;
        int d = av - bv;
        s += (unsigned int)(d < 0 ? -d : d);
    }
    return s;
#endif
}

__global__ __launch_bounds__(256, 4) void k_fused(const float* __restrict__ sino,
                                                  float* __restrict__ pmin,
                                                  float* __restrict__ pmax,
                                                  unsigned char* __restrict__ pat,
                                                  float* __restrict__ out,
                                                  int G){
    cg::grid_group gridg = cg::this_grid();
    int tid = threadIdx.x;
    int lane = tid & 63, wv = tid >> 6;

    __shared__ unsigned int hist[4096];    // 64x64 joint histogram (16 KB)
    __shared__ uint4 selw4[64];            // selected patch (1 KB)
    __shared__ unsigned int distArr[25];
    __shared__ int bestCid;
    __shared__ float sH[8];

    // ---------------- phase 1: per-batch min/max partials ----------------
    // 64 batches x 16 parts; each part = 2304 float4 (9 per thread)
    for (int t = blockIdx.x; t < NB * NPART; t += G){
        int b = t >> 4, part = t & 15;
        const float4* src = (const float4*)(sino + (size_t)b * (H_ * W_));
        int base = part * 2304 + tid;
        float mn = 1e30f, mx = -1e30f;
        #pragma unroll
        for (int k = 0; k < 9; k++){
            float4 v = src[base + k * 256];
            mn = fminf(mn, fminf(fminf(v.x, v.y), fminf(v.z, v.w)));
            mx = fmaxf(mx, fmaxf(fmaxf(v.x, v.y), fmaxf(v.z, v.w)));
        }
        #pragma unroll
        for (int off = 32; off > 0; off >>= 1){
            mn = fminf(mn, __shfl_down(mn, off));
            mx = fmaxf(mx, __shfl_down(mx, off));
        }
        if (lane == 0){ sH[wv] = mn; sH[4 + wv] = mx; }
        __syncthreads();
        if (tid == 0){
            mn = fminf(fminf(sH[0], sH[1]), fminf(sH[2], sH[3]));
            mx = fmaxf(fmaxf(sH[4], sH[5]), fmaxf(sH[6], sH[7]));
            pmin[t] = mn;          // race-free overwrite, no init needed
            pmax[t] = mx;
        }
        __syncthreads();
    }

    gridg.sync();

    // ---------------- phase 2: bin to uint8 patches ----------------
    for (int t = blockIdx.x; t < NB * NP; t += G){
        int b = t / NP;
        int p = t % NP;
        int pr = p / NC, pc = p % NC;
        float mn = 1e30f, mx = -1e30f;
        #pragma unroll
        for (int k = 0; k < NPART; k++){          // uniform addresses -> scalar loads
            mn = fminf(mn, pmin[b * NPART + k]);
            mx = fmaxf(mx, pmax[b * NPART + k]);
        }
        float denom = mx - mn + 1e-6f;
        int i  = tid >> 3;            // row in patch (32 rows, 8 threads/row)
        int j4 = (tid & 7) << 2;      // col in patch, multiple of 4
        const float* rowp = sino + ((size_t)b * H_ + (size_t)(pr * 32 + i)) * W_ + pc * 32 + j4;
        float4 v = *(const float4*)rowp;
        uchar4 o;
        o.x = (unsigned char)binval(v.x, mn, denom);
        o.y = (unsigned char)binval(v.y, mn, denom);
        o.z = (unsigned char)binval(v.z, mn, denom);
        o.w = (unsigned char)binval(v.w, mn, denom);
        *(uchar4*)(pat + (size_t)t * PE + tid * 4) = o;
    }

    gridg.sync();

    // ---------------- phase 3: NLM-match + joint histogram + MI ----------------
    for (int t = blockIdx.x; t < NB * NSEL; t += G){
        int b = t / NSEL;
        int s = t % NSEL;
        int sr = (s / 6) * 2, sc = (s % 6) * 2;
        int pself = sr * NC + sc;
        const unsigned char* batch = pat + (size_t)b * NP * PE;

        #pragma unroll
        for (int k = 0; k < 16; k++) hist[k * 256 + tid] = 0;
        ((unsigned int*)selw4)[tid] = ((const unsigned int*)(batch + (size_t)pself * PE))[tid];
        __syncthreads();

        // distances: wave wv handles candidates c = wv, wv+4, ...
        for (int c = wv; c < 25; c += 4){
            int dr = c / 5 - 2, dc = c % 5 - 2;
            int rr = min(max(sr + dr, 0), NR - 1);
            int cc = min(max(sc + dc, 0), NC - 1);
            int cid = rr * NC + cc;
            unsigned int dist = 0xFFFFFFFFu;   // masked (self / clipped-onto-self) sentinel
            if (cid != pself){
                uint4 cv = ((const uint4*)(batch + (size_t)cid * PE))[lane];
                uint4 sv = selw4[lane];
                dist = bytesad(cv.x, sv.x, 0u);
                dist = bytesad(cv.y, sv.y, dist);
                dist = bytesad(cv.z, sv.z, dist);
                dist = bytesad(cv.w, sv.w, dist);
                #pragma unroll
                for (int off = 32; off > 0; off >>= 1) dist += __shfl_down(dist, off);
            }
            if (lane == 0) distArr[c] = dist;
        }
        __syncthreads();

        if (tid == 0){
            unsigned int bd = 0xFFFFFFFFu; int bc = 0;
            #pragma unroll
            for (int c = 0; c < 25; c++){
                if (distArr[c] < bd){ bd = distArr[c]; bc = c; }   // strict <: first-min like argmin
            }
            int dr = bc / 5 - 2, dc = bc % 5 - 2;
            int rr = min(max(sr + dr, 0), NR - 1);
            int cc = min(max(sc + dc, 0), NC - 1);
            bestCid = rr * NC + cc;
        }
        __syncthreads();

        // joint histogram: each thread handles 4 elements
        {
            unsigned int bw = ((const unsigned int*)(batch + (size_t)bestCid * PE))[tid];
            unsigned int sw = ((const unsigned int*)selw4)[tid];
            #pragma unroll
            for (int k = 0; k < 4; k++){
                unsigned int sv = (sw >> (8 * k)) & 255u;
                unsigned int bv = (bw >> (8 * k)) & 255u;
                atomicAdd(&hist[sv * 64 + bv], 1u);
            }
        }
        __syncthreads();

        const float invP = 1.0f / 1024.0f;
        // h_xy partial: 16 bins per thread; skip empty bins (exact: term is 0.0)
        float part = 0.0f;
        #pragma unroll
        for (int k = 0; k < 16; k++){
            unsigned int cnt = hist[k * 256 + tid];
            if (cnt){
                float pj = (float)cnt * invP;
                part -= pj * __logf(pj + 1e-8f);
            }
        }
        #pragma unroll
        for (int off = 32; off > 0; off >>= 1) part += __shfl_down(part, off);
        if (lane == 0) sH[4 + wv] = part;

        // marginals: wave0 -> p_x (rows), wave1 -> p_y (cols); diagonal reads avoid bank conflicts
        if (tid < 128){
            int isY = tid >> 6;
            int tt = tid & 63;
            unsigned int cnt = 0;
            if (!isY){
                for (int k = 0; k < 64; k++) cnt += hist[tt * 64 + ((k + tt) & 63)];
            } else {
                for (int k = 0; k < 64; k++) cnt += hist[((k + tt) & 63) * 64 + tt];
            }
            float pm = (float)cnt * invP;
            float term = (cnt ? -pm * __logf(pm + 1e-8f) : 0.0f);
            #pragma unroll
            for (int off = 32; off > 0; off >>= 1) term += __shfl_down(term, off);
            if (tt == 0) sH[isY] = term;
        }
        __syncthreads();

        if (tid == 0){
            float hx = sH[0], hy = sH[1];
            float hxy = sH[4] + sH[5] + sH[6] + sH[7];
            float mi = hx + hy - hxy;
            out[t] = log1pf(mi);
        }
        // next iteration's hist re-init is safe: all hist/selw4 reads happened
        // before the __syncthreads above; sH is re-written only after 4 more syncs.
    }
}

extern "C" void kernel_launch(void* const* d_in, const int* in_sizes, int n_in,
                              void* d_out, int out_size, void* d_ws, size_t ws_size,
                              hipStream_t stream) {
    const float* sino = (const float*)d_in[0];
    float* out = (float*)d_out;
    unsigned char* ws = (unsigned char*)d_ws;
    float* pmin = (float*)ws;
    float* pmax = (float*)(ws + 4096);
    unsigned char* pat = ws + 8192;

    // co-residency-safe grid: __launch_bounds__(256,4) guarantees >=4 blocks/CU
    // (VGPR<=128, LDS 17.3KB*4=69KB<160KB); clamp with the runtime query anyway.
    int perCU = 0;
    hipError_t e = hipOccupancyMaxActiveBlocksPerMultiprocessor(&perCU, (const void*)k_fused, 256, 0);
    if (e != hipSuccess || perCU <= 0) perCU = 4;
    int G = perCU * 256;          // 256 CUs on MI355X
    if (G > 1024) G = 1024;       // work layout target; grid-stride handles any G

    void* args[] = { (void*)&sino, (void*)&pmin, (void*)&pmax,
                     (void*)&pat, (void*)&out, (void*)&G };
    hipLaunchCooperativeKernel((const void*)k_fused, dim3(G), dim3(256), args, 0, stream);
}

// Round 4
// 35.744 us; speedup vs baseline: 5.2556x; 5.2556x over previous
//
#include <hip/hip_runtime.h>
#include <math.h>

#define NB   64
#define H_   384
#define W_   384
#define NR   12
#define NC   12
#define NP   144     // patches per batch
#define PE   1024    // elements per patch
#define NSEL 36
#define NPART 8      // min/max partials per batch

// ws layout:
// [0, 2048):            float pmin[64][8]
// [2048, 4096):         float pmax[64][8]
// [4096, 4096+64*144*1024): uint8 binned patches [B][144][1024]

__global__ __launch_bounds__(256) void k_minmax(const float* __restrict__ sino,
                                                float* __restrict__ pmin,
                                                float* __restrict__ pmax){
    int b = blockIdx.x >> 3;
    int part = blockIdx.x & 7;
    const float4* src = (const float4*)(sino + (size_t)b * (H_ * W_));
    int base = part * 4608 + threadIdx.x;   // 36864 float4 / batch, 4608 / part
    float mn = 1e30f, mx = -1e30f;
    #pragma unroll
    for (int k = 0; k < 18; k++){
        float4 v = src[base + k * 256];
        mn = fminf(mn, fminf(fminf(v.x, v.y), fminf(v.z, v.w)));
        mx = fmaxf(mx, fmaxf(fmaxf(v.x, v.y), fmaxf(v.z, v.w)));
    }
    #pragma unroll
    for (int off = 32; off > 0; off >>= 1){
        mn = fminf(mn, __shfl_down(mn, off));
        mx = fmaxf(mx, __shfl_down(mx, off));
    }
    __shared__ float smn[4], smx[4];
    int lane = threadIdx.x & 63, wv = threadIdx.x >> 6;
    if (lane == 0){ smn[wv] = mn; smx[wv] = mx; }
    __syncthreads();
    if (threadIdx.x == 0){
        mn = fminf(fminf(smn[0], smn[1]), fminf(smn[2], smn[3]));
        mx = fmaxf(fmaxf(smx[0], smx[1]), fmaxf(smx[2], smx[3]));
        pmin[b * NPART + part] = mn;   // race-free overwrite: no init needed
        pmax[b * NPART + part] = mx;
    }
}

__device__ inline int binval(float x, float mn, float denom){
    float nrm = (x - mn) / denom;                 // mirror reference op order exactly
    nrm = fminf(fmaxf(nrm, 0.0f), 1.0f);
    int bn = (int)(nrm * 63.0f);                  // truncation, like astype(int32)
    bn = bn < 0 ? 0 : (bn > 63 ? 63 : bn);
    return bn;
}

// 4 patches (one 32x128 strip) per block: 2304 blocks instead of 9216
__global__ __launch_bounds__(256) void k_bin(const float* __restrict__ sino,
                                             const float* __restrict__ pmin,
                                             const float* __restrict__ pmax,
                                             unsigned char* __restrict__ pat){
    int bid = blockIdx.x;
    int b = bid / 36;
    int rem = bid % 36;
    int prow = rem / 3;
    int strip = rem % 3;                 // 4 patches: pc = strip*4 + k
    float mn = 1e30f, mx = -1e30f;
    #pragma unroll
    for (int k = 0; k < NPART; k++){     // uniform addresses -> scalar loads
        mn = fminf(mn, pmin[b * NPART + k]);
        mx = fmaxf(mx, pmax[b * NPART + k]);
    }
    float denom = mx - mn + 1e-6f;
    int tid = threadIdx.x;
    int irow = tid >> 3;                 // 0..31 row within strip
    int tc   = tid & 7;                  // float4 index within a 32-col patch
    const float4* rowp = (const float4*)(sino + ((size_t)b * H_ + (size_t)(prow * 32 + irow)) * W_ + strip * 128);
    unsigned char* pbase = pat + ((size_t)(b * NP + prow * NC + strip * 4)) * PE + irow * 32 + tc * 4;
    #pragma unroll
    for (int k = 0; k < 4; k++){
        float4 v = rowp[tc + k * 8];
        uchar4 o;
        o.x = (unsigned char)binval(v.x, mn, denom);
        o.y = (unsigned char)binval(v.y, mn, denom);
        o.z = (unsigned char)binval(v.z, mn, denom);
        o.w = (unsigned char)binval(v.w, mn, denom);
        *(uchar4*)(pbase + (size_t)k * PE) = o;
    }
}

__device__ inline unsigned int bytesad(unsigned int a, unsigned int b, unsigned int acc){
#if __has_builtin(__builtin_amdgcn_sad_u8)
    return __builtin_amdgcn_sad_u8(a, b, acc);
#else
    unsigned int s = acc;
    #pragma unroll
    for (int k = 0; k < 4; k++){
        int av = (a >> (8 * k)) & 255;
        int bv = (b >> (8 * k)) & 255;
        int d = av - bv;
        s += (unsigned int)(d < 0 ? -d : d);
    }
    return s;
#endif
}

__global__ __launch_bounds__(256) void k_mi(const unsigned char* __restrict__ pat,
                                            float* __restrict__ out){
    int b = blockIdx.x / NSEL;
    int s = blockIdx.x % NSEL;
    int sr = (s / 6) * 2, sc = (s % 6) * 2;
    int pself = sr * NC + sc;
    const unsigned char* batch = pat + (size_t)b * NP * PE;

    __shared__ uint4 selw4[64];            // selected patch, 1024 bytes
    __shared__ unsigned int hist[4096];    // 64x64 joint histogram
    __shared__ unsigned int distArr[25];
    __shared__ int bestCid;
    __shared__ float sHx[4], sHy[4], sHxy[4];

    int tid = threadIdx.x;
    int lane = tid & 63, wv = tid >> 6;

    {   // zero hist with b128 stores
        uint4 z = {0u, 0u, 0u, 0u};
        uint4* h4 = (uint4*)hist;
        #pragma unroll
        for (int k = 0; k < 4; k++) h4[k * 256 + tid] = z;
    }
    ((unsigned int*)selw4)[tid] = ((const unsigned int*)(batch + (size_t)pself * PE))[tid];
    __syncthreads();

    // distances: 16 lanes per candidate, 4 candidates per wave, 2 rounds
    int grp = lane >> 4;                   // 0..3 candidate slot within wave
    int sl  = lane & 15;                   // 16-byte chunk index
    #pragma unroll
    for (int r = 0; r < 2; r++){
        int c = r * 16 + wv * 4 + grp;
        if (c < 25){
            int dr = c / 5 - 2, dc = c % 5 - 2;
            int rr = min(max(sr + dr, 0), NR - 1);
            int cc = min(max(sc + dc, 0), NC - 1);
            int cid = rr * NC + cc;
            const uint4* cp = (const uint4*)(batch + (size_t)cid * PE);
            unsigned int dist = 0;
            #pragma unroll
            for (int k = 0; k < 4; k++){
                uint4 cv = cp[sl + 16 * k];
                uint4 sv = selw4[sl + 16 * k];   // same addr across 16-lane groups: broadcast
                dist = bytesad(cv.x, sv.x, dist);
                dist = bytesad(cv.y, sv.y, dist);
                dist = bytesad(cv.z, sv.z, dist);
                dist = bytesad(cv.w, sv.w, dist);
            }
            #pragma unroll
            for (int off = 8; off > 0; off >>= 1) dist += __shfl_xor(dist, off);
            if (sl == 0) distArr[c] = (cid == pself) ? 0xFFFFFFFFu : dist;
        }
    }
    __syncthreads();

    if (tid == 0){
        unsigned int bd = 0xFFFFFFFFu; int bc = 0;
        #pragma unroll
        for (int c = 0; c < 25; c++){
            if (distArr[c] < bd){ bd = distArr[c]; bc = c; }   // strict <: first-min like argmin
        }
        int dr = bc / 5 - 2, dc = bc % 5 - 2;
        int rr = min(max(sr + dr, 0), NR - 1);
        int cc = min(max(sc + dc, 0), NC - 1);
        bestCid = rr * NC + cc;
    }
    __syncthreads();

    // joint histogram: each thread handles 4 elements
    {
        unsigned int bw = ((const unsigned int*)(batch + (size_t)bestCid * PE))[tid];
        unsigned int sw = ((const unsigned int*)selw4)[tid];
        #pragma unroll
        for (int k = 0; k < 4; k++){
            unsigned int sv = (sw >> (8 * k)) & 255u;
            unsigned int bv = (bw >> (8 * k)) & 255u;
            atomicAdd(&hist[sv * 64 + bv], 1u);
        }
    }
    __syncthreads();

    const float invP = 1.0f / 1024.0f;

    // h_xy partial: 16 bins per thread; skip empty bins (exact: term is 0.0)
    {
        float part = 0.0f;
        #pragma unroll
        for (int k = 0; k < 16; k++){
            unsigned int cnt = hist[k * 256 + tid];
            if (cnt){
                float pj = (float)cnt * invP;
                part -= pj * __logf(pj + 1e-8f);
            }
        }
        #pragma unroll
        for (int off = 32; off > 0; off >>= 1) part += __shfl_down(part, off);
        if (lane == 0) sHxy[wv] = part;
    }

    // p_x: 4 threads per row, 16 consecutive reads each (2-way conflict: free)
    {
        int r = tid >> 2, q = tid & 3;
        unsigned int cnt = 0;
        #pragma unroll
        for (int i = 0; i < 16; i++) cnt += hist[r * 64 + q * 16 + i];
        cnt += __shfl_xor(cnt, 1);
        cnt += __shfl_xor(cnt, 2);
        float term = 0.0f;
        if (q == 0 && cnt){
            float pm = (float)cnt * invP;
            term = -pm * __logf(pm + 1e-8f);
        }
        #pragma unroll
        for (int off = 32; off > 0; off >>= 1) term += __shfl_down(term, off);
        if (lane == 0) sHx[wv] = term;
    }

    // p_y: 4 threads per column, stride-64 reads (4-way conflict: 1.58x, 16 reads)
    {
        int c = tid >> 2, q = tid & 3;
        unsigned int cnt = 0;
        #pragma unroll
        for (int i = 0; i < 16; i++) cnt += hist[(q * 16 + i) * 64 + c];
        cnt += __shfl_xor(cnt, 1);
        cnt += __shfl_xor(cnt, 2);
        float term = 0.0f;
        if (q == 0 && cnt){
            float pm = (float)cnt * invP;
            term = -pm * __logf(pm + 1e-8f);
        }
        #pragma unroll
        for (int off = 32; off > 0; off >>= 1) term += __shfl_down(term, off);
        if (lane == 0) sHy[wv] = term;
    }
    __syncthreads();

    if (tid == 0){
        float hx  = sHx[0] + sHx[1] + sHx[2] + sHx[3];
        float hy  = sHy[0] + sHy[1] + sHy[2] + sHy[3];
        float hxy = sHxy[0] + sHxy[1] + sHxy[2] + sHxy[3];
        float mi = hx + hy - hxy;
        out[blockIdx.x] = log1pf(mi);
    }
}

extern "C" void kernel_launch(void* const* d_in, const int* in_sizes, int n_in,
                              void* d_out, int out_size, void* d_ws, size_t ws_size,
                              hipStream_t stream) {
    const float* sino = (const float*)d_in[0];
    float* out = (float*)d_out;
    unsigned char* ws = (unsigned char*)d_ws;
    float* pmin = (float*)ws;
    float* pmax = (float*)(ws + 2048);
    unsigned char* pat = ws + 4096;

    k_minmax<<<NB * NPART, 256, 0, stream>>>(sino, pmin, pmax);
    k_bin<<<NB * 36, 256, 0, stream>>>(sino, pmin, pmax, pat);
    k_mi<<<NB * NSEL, 256, 0, stream>>>(pat, out);
}